// Round 8
// baseline (464.166 us; speedup 1.0000x reference)
//
#include <hip/hip_runtime.h>

// MGNConv fused-MFMA, round 8: resubmit of round 7 after infra failure.
// 16-wave block + __launch_bounds__(1024, 1).
//   edge_out[e,k] = sum_{c,ab} hs[e,c] * o[e,ab] * w2[c, ab*8+k]
//   hs = silu(emb@w1/4)/64  (folds both 1/8 path norms)
//   o[e,ab] = attr[e, ab>>4] * z[e, ab&15],  z = cat(x[vi], x[vj])
// Calibrated launch_bounds model (2nd arg = min BLOCKS/CU, CUDA-style):
//   (512,2)->4 waves/EU cap128 OK | (512,4)->8/EU cap64 SPILL |
//   (1024) bare->heuristic 2 blocks=8/EU cap64 SPILL | waves_per_eu ignored.
// => (1024,1): 1 block x 16 waves / 4 SIMD = 4 waves/EU -> VGPR cap 128.
// No other changes vs rounds 5/6 (structure correct, occupancy 41% proven).

typedef __attribute__((ext_vector_type(8))) short short8;
typedef __attribute__((ext_vector_type(4))) float floatx4;

__device__ inline unsigned short f2bf(float f) {
    union { float f; unsigned u; } v; v.f = f;
    unsigned r = v.u + 0x7FFFu + ((v.u >> 16) & 1u);
    return (unsigned short)(r >> 16);
}

__device__ inline unsigned cvt_pk_bf16(float lo, float hi) {
    unsigned r;
    asm("v_cvt_pk_bf16_f32 %0, %1, %2" : "=v"(r) : "v"(lo), "v"(hi));
    return r;
}

constexpr int TB    = 1024;  // 16 waves, one block per CU
constexpr int NBLK  = 256;
constexpr int NWAVE = TB / 64;

constexpr int AT_LDF = 32;   // per wave [4][32] f32

__global__ __launch_bounds__(TB, 1)
void edge_kernel(
    const float* __restrict__ x,          // [N,8]
    const int*   __restrict__ ei,         // [2,E]
    const float* __restrict__ attr,       // [E,4]
    const float* __restrict__ emb,        // [E,16]
    const float* __restrict__ w1,         // [16,64]
    const float* __restrict__ w2,         // [64,512]
    float* __restrict__ edge_out,         // [E,8]
    float* __restrict__ e_sum,            // [N,8] pre-zeroed
    int E)
{
    // w2 transposed, bf16, XOR-swizzled: s_w2t[n*64 + (k ^ ((n&7)<<3))] = w2[k][n]
    __shared__ __align__(16) unsigned short s_w2t[512 * 64];        // 65536 B
    // z features f32, per wave: [16 feat][32 edge]; stride 32 f32 = bank period
    __shared__ __align__(16) float          s_ztA[NWAVE * 16 * 32]; // 32768 B
    __shared__ __align__(16) float          s_atA[NWAVE * 4 * AT_LDF]; // 8192 B
    __shared__ int                          s_vjA[NWAVE * 32];      //  2048 B
    // total = 108544 B -> one 16-wave block per CU (4 waves/SIMD)

    const int tid  = threadIdx.x;
    const int wave = tid >> 6;
    const int lane = tid & 63;
    const int m16  = lane & 15;
    const int quad = lane >> 4;
    const int par  = m16 >> 3;

    // ---- stage w2 transposed+swizzled to bf16 ----
    for (int idx = tid; idx < 512 * 64; idx += TB) {
        const int n = idx & 511, k = idx >> 9;
        s_w2t[n * 64 + (k ^ ((n & 7) << 3))] = f2bf(w2[k * 512 + n]);
    }
    __syncthreads();   // only barrier; steady loop is wave-private

    // ---- layer-1 w1 fragments (zero-padded K 16->32).
    // A-operand of the TRANSPOSED layer-1: A[m=chan mt*16+m16][k=quad*8+j] = w1[k][chan].
    short8 w1f[4];
    #pragma unroll
    for (int mt = 0; mt < 4; ++mt) {
        short8 f;
        if (quad < 2) {
            #pragma unroll
            for (int j = 0; j < 8; ++j)
                f[j] = (short)f2bf(w1[(quad * 8 + j) * 64 + mt * 16 + m16]);
        } else {
            #pragma unroll
            for (int j = 0; j < 8; ++j) f[j] = 0;
        }
        w1f[mt] = f;
    }

    float* ztw = s_ztA + wave * 16 * 32;
    float* atw = s_atA + wave * 4 * AT_LDF;
    int*   vjw = s_vjA + wave * 32;

    const int  wid = blockIdx.x * NWAVE + wave;
    const int  nw  = NBLK * NWAVE;
    const int  ntiles = E >> 5;   // E divisible by 32 (800000)
    const bool stg = (quad < 2);
    const int  mst = quad * 16 + m16;   // == lane for stg lanes (0..31)

    // a2-gather shuffle source lanes
    const int srcA = m16 + 16 * ((2 * quad) & 3);
    const int srcB = m16 + 16 * ((2 * quad + 1) & 3);

    // swizzled b2 element offsets
    const int swz = (m16 & 7) << 3;
    const int o0  = (quad * 8) ^ swz;
    const int o1  = o0 ^ 32;

    // ---- pipeline registers (valid on stg lanes) ----
    float4 xi0, xi1, xj0, xj1, a4;
    float4 em0a, em0b, em1a, em1b;
    int viN = 0, vjN = 0, vjC = 0;

    // ---- prologue: tile wid data + ei for tile wid+nw ----
    if (wid < ntiles && stg) {
        const int e0 = (wid << 5) + mst;
        const int vi = ei[e0];
        vjC = ei[E + e0];
        xi0 = *(const float4*)(x + (size_t)vi * 8);
        xi1 = *(const float4*)(x + (size_t)vi * 8 + 4);
        xj0 = *(const float4*)(x + (size_t)vjC * 8);
        xj1 = *(const float4*)(x + (size_t)vjC * 8 + 4);
        a4  = *(const float4*)(attr + (size_t)e0 * 4);
        const float* ep0 = emb + (size_t)((wid << 5) + m16) * 16 + quad * 8;
        em0a = *(const float4*)ep0;
        em0b = *(const float4*)(ep0 + 4);
        const float* ep1 = emb + (size_t)((wid << 5) + 16 + m16) * 16 + quad * 8;
        em1a = *(const float4*)ep1;
        em1b = *(const float4*)(ep1 + 4);
        const int t1 = (wid + nw < ntiles) ? (wid + nw) : wid;
        const int e1 = (t1 << 5) + mst;
        viN = ei[e1];
        vjN = ei[E + e1];
    }

    for (int tile = wid; tile < ntiles; tile += nw) {
        const int base = tile << 5;

        // ---- A: stage z/attr/vj (regs -> wave-private LDS) ----
        if (stg) {
            ztw[ 0*32+mst]=xi0.x; ztw[ 1*32+mst]=xi0.y;
            ztw[ 2*32+mst]=xi0.z; ztw[ 3*32+mst]=xi0.w;
            ztw[ 4*32+mst]=xi1.x; ztw[ 5*32+mst]=xi1.y;
            ztw[ 6*32+mst]=xi1.z; ztw[ 7*32+mst]=xi1.w;
            ztw[ 8*32+mst]=xj0.x; ztw[ 9*32+mst]=xj0.y;
            ztw[10*32+mst]=xj0.z; ztw[11*32+mst]=xj0.w;
            ztw[12*32+mst]=xj1.x; ztw[13*32+mst]=xj1.y;
            ztw[14*32+mst]=xj1.z; ztw[15*32+mst]=xj1.w;
            atw[0*AT_LDF+mst]=a4.x;   atw[1*AT_LDF+mst]=a4.y;
            atw[2*AT_LDF+mst]=a4.z;   atw[3*AT_LDF+mst]=a4.w;
            vjw[mst] = vjC;
        }

        short8 a1[2];
        {
            union { short8 s8; unsigned u[4]; } uu;
            if (stg) {
                uu.u[0] = cvt_pk_bf16(em0a.x, em0a.y);
                uu.u[1] = cvt_pk_bf16(em0a.z, em0a.w);
                uu.u[2] = cvt_pk_bf16(em0b.x, em0b.y);
                uu.u[3] = cvt_pk_bf16(em0b.z, em0b.w);
            } else {
                uu.u[0]=0u; uu.u[1]=0u; uu.u[2]=0u; uu.u[3]=0u;
            }
            a1[0] = uu.s8;
            if (stg) {
                uu.u[0] = cvt_pk_bf16(em1a.x, em1a.y);
                uu.u[1] = cvt_pk_bf16(em1a.z, em1a.w);
                uu.u[2] = cvt_pk_bf16(em1b.x, em1b.y);
                uu.u[3] = cvt_pk_bf16(em1b.z, em1b.w);
            } else {
                uu.u[0]=0u; uu.u[1]=0u; uu.u[2]=0u; uu.u[3]=0u;
            }
            a1[1] = uu.s8;
        }

        // ---- B: issue next-tile loads into the just-consumed registers ----
        {
            const int tn     = tile + nw;
            const int tn_cl  = (tn  < ntiles) ? tn  : tile;
            const int tnn    = tn + nw;
            const int tnn_cl = (tnn < ntiles) ? tnn : tn_cl;
            if (stg) {
                const int en = (tn_cl << 5) + mst;
                vjC = vjN;   // vj of tile tn, staged at next A
                xi0 = *(const float4*)(x + (size_t)viN * 8);
                xi1 = *(const float4*)(x + (size_t)viN * 8 + 4);
                xj0 = *(const float4*)(x + (size_t)vjN * 8);
                xj1 = *(const float4*)(x + (size_t)vjN * 8 + 4);
                a4  = *(const float4*)(attr + (size_t)en * 4);
                const float* ep0 = emb + (size_t)((tn_cl << 5) + m16) * 16 + quad * 8;
                em0a = *(const float4*)ep0;
                em0b = *(const float4*)(ep0 + 4);
                const float* ep1 = emb + (size_t)((tn_cl << 5) + 16 + m16) * 16 + quad * 8;
                em1a = *(const float4*)ep1;
                em1b = *(const float4*)(ep1 + 4);
                const int enn = (tnn_cl << 5) + mst;
                viN = ei[enn];
                vjN = ei[E + enn];
            }
        }

        // ---- C: TRANSPOSED layer-1 MFMA -> silu -> a2 frags via shuffles.
        // C' = w1T @ embT: lane (m16,quad) holds edge s*16+m16,
        // chans {16mt + 4quad + r}. a2[s][qq] needs chans qq*32+quad*8+0..7
        // of the same edge. word w (chans c0=qq*32+quad*8+2w, c0+1) comes from
        // lane (m16, q'=(2quad+(w>>1))&3), reg p[mt'=2qq+(quad>>1)][w&1].
        short8 a2[2][2];
        #pragma unroll
        for (int s = 0; s < 2; ++s) {
            unsigned p[4][2];
            // pairs: keeps only 2 C-fragments (8 regs) live at a time
            #pragma unroll
            for (int half = 0; half < 2; ++half) {
                floatx4 c0, c1;
                {
                    floatx4 z4 = {0.f, 0.f, 0.f, 0.f};
                    c0 = __builtin_amdgcn_mfma_f32_16x16x32_bf16(w1f[2*half    ], a1[s], z4, 0, 0, 0);
                    c1 = __builtin_amdgcn_mfma_f32_16x16x32_bf16(w1f[2*half + 1], a1[s], z4, 0, 0, 0);
                }
                #pragma unroll
                for (int h = 0; h < 2; ++h) {
                    const floatx4& c = h ? c1 : c0;
                    float sv[4];
                    #pragma unroll
                    for (int r = 0; r < 4; ++r) {
                        const float u   = c[r] * 0.25f;               // /sqrt(16)
                        const float den = 1.f + __expf(-u);
                        sv[r] = u * __builtin_amdgcn_rcpf(den) * 0.015625f; // /64
                    }
                    p[2*half + h][0] = cvt_pk_bf16(sv[0], sv[1]);
                    p[2*half + h][1] = cvt_pk_bf16(sv[2], sv[3]);
                }
            }
            #pragma unroll
            for (int qq = 0; qq < 2; ++qq) {
                union { short8 s8; unsigned u[4]; } uu;
                #pragma unroll
                for (int w = 0; w < 4; ++w) {
                    const int srcLane = (w < 2) ? srcA : srcB;
                    const unsigned vA = (unsigned)__shfl((int)p[2*qq    ][w & 1], srcLane, 64);
                    const unsigned vB = (unsigned)__shfl((int)p[2*qq + 1][w & 1], srcLane, 64);
                    uu.u[w] = (quad & 2) ? vB : vA;
                }
                a2[s][qq] = uu.s8;
            }
        }

        float eacc[2][4];
        #pragma unroll
        for (int s = 0; s < 2; ++s)
            #pragma unroll
            for (int r = 0; r < 4; ++r) eacc[s][r] = 0.f;

        // ---- D: N loop, defer-attr epilogue; attr from wave-private LDS.
        // b_idx = (2t+par)&15 == (2tt+par)&15 (g-independent)
        __builtin_amdgcn_s_setprio(1);
        #pragma unroll 1
        for (int g = 0; g < 4; ++g) {
            float av[2][4];
            #pragma unroll
            for (int s = 0; s < 2; ++s) {
                const float4 a4v = *(const float4*)(atw + g * AT_LDF + s * 16 + quad * 4);
                av[s][0] = a4v.x; av[s][1] = a4v.y;
                av[s][2] = a4v.z; av[s][3] = a4v.w;
            }

            float tacc[2][4];
            #pragma unroll
            for (int s = 0; s < 2; ++s)
                #pragma unroll
                for (int r = 0; r < 4; ++r) tacc[s][r] = 0.f;

            #pragma unroll
            for (int tt = 0; tt < 8; ++tt) {
                const int t = g * 8 + tt;
                const unsigned short* wrow = s_w2t + (16 * t + m16) * 64;
                short8 b2[2];
                b2[0] = *(const short8*)(wrow + o0);
                b2[1] = *(const short8*)(wrow + o1);
                const int b_idx = (2 * tt + par) & 15;
                #pragma unroll
                for (int s = 0; s < 2; ++s) {
                    floatx4 c = {0.f, 0.f, 0.f, 0.f};
                    c = __builtin_amdgcn_mfma_f32_16x16x32_bf16(a2[s][0], b2[0], c, 0, 0, 0);
                    c = __builtin_amdgcn_mfma_f32_16x16x32_bf16(a2[s][1], b2[1], c, 0, 0, 0);
                    const float4 zv = *(const float4*)(ztw + b_idx * 32 + s * 16 + quad * 4);
                    tacc[s][0] = fmaf(c[0], zv.x, tacc[s][0]);
                    tacc[s][1] = fmaf(c[1], zv.y, tacc[s][1]);
                    tacc[s][2] = fmaf(c[2], zv.z, tacc[s][2]);
                    tacc[s][3] = fmaf(c[3], zv.w, tacc[s][3]);
                }
            }
            #pragma unroll
            for (int s = 0; s < 2; ++s)
                #pragma unroll
                for (int r = 0; r < 4; ++r)
                    eacc[s][r] = fmaf(av[s][r], tacc[s][r], eacc[s][r]);
        }
        __builtin_amdgcn_s_setprio(0);

        // ---- E: reduce ab-parity (lanes col and col^8), then write ----
        #pragma unroll
        for (int s = 0; s < 2; ++s)
            #pragma unroll
            for (int r = 0; r < 4; ++r)
                eacc[s][r] += __shfl_xor(eacc[s][r], 8, 64);

        if (m16 < 8) {
            #pragma unroll
            for (int s = 0; s < 2; ++s) {
                const int4 vjq = *(const int4*)(vjw + s * 16 + quad * 4);
                const int vjr[4] = {vjq.x, vjq.y, vjq.z, vjq.w};
                #pragma unroll
                for (int r = 0; r < 4; ++r) {
                    const int e = base + s * 16 + quad * 4 + r;
                    edge_out[(size_t)e * 8 + m16] = eacc[s][r];
                    atomicAdd(e_sum + (size_t)vjr[r] * 8 + m16, eacc[s][r]);
                }
            }
        }
    }
}

__global__ __launch_bounds__(256) void node_kernel(
    const float* __restrict__ x,       // [N,8]
    const float* __restrict__ e_sum,   // [N,8]
    const float* __restrict__ w_node,  // [8,8,16]
    float* __restrict__ x_out,         // [N,16]
    int N)
{
    __shared__ float s_w[8 * 8 * 16];
    for (int idx = threadIdx.x; idx < 1024; idx += 256) s_w[idx] = w_node[idx];
    __syncthreads();

    const int n = blockIdx.x * 256 + threadIdx.x;
    if (n >= N) return;

    float xa[8], eb[8];
    #pragma unroll
    for (int a = 0; a < 8; ++a) xa[a] = x[(size_t)n * 8 + a];
    #pragma unroll
    for (int b = 0; b < 8; ++b) eb[b] = e_sum[(size_t)n * 8 + b];

    float out[16];
    #pragma unroll
    for (int k = 0; k < 16; ++k) out[k] = 0.f;

    const float4* wv = (const float4*)s_w;
    #pragma unroll
    for (int a = 0; a < 8; ++a) {
        #pragma unroll
        for (int b = 0; b < 8; ++b) {
            const float t = xa[a] * eb[b] * 0.125f;
            #pragma unroll
            for (int k4 = 0; k4 < 4; ++k4) {
                const float4 w = wv[(a * 8 + b) * 4 + k4];
                out[k4 * 4 + 0] = fmaf(t, w.x, out[k4 * 4 + 0]);
                out[k4 * 4 + 1] = fmaf(t, w.y, out[k4 * 4 + 1]);
                out[k4 * 4 + 2] = fmaf(t, w.z, out[k4 * 4 + 2]);
                out[k4 * 4 + 3] = fmaf(t, w.w, out[k4 * 4 + 3]);
            }
        }
    }

    float4* xo = (float4*)(x_out + (size_t)n * 16);
    #pragma unroll
    for (int k4 = 0; k4 < 4; ++k4)
        xo[k4] = make_float4(out[k4 * 4 + 0], out[k4 * 4 + 1],
                             out[k4 * 4 + 2], out[k4 * 4 + 3]);
}

extern "C" void kernel_launch(void* const* d_in, const int* in_sizes, int n_in,
                              void* d_out, int out_size, void* d_ws, size_t ws_size,
                              hipStream_t stream) {
    const float* x      = (const float*)d_in[0];
    const int*   ei     = (const int*)d_in[1];
    const float* attr   = (const float*)d_in[2];
    const float* emb    = (const float*)d_in[3];
    const float* w1     = (const float*)d_in[4];
    const float* w2     = (const float*)d_in[5];
    const float* w_node = (const float*)d_in[6];

    const int N = in_sizes[0] / 8;   // 50000
    const int E = in_sizes[2] / 4;   // 800000

    float* x_out    = (float*)d_out;                   // [N,16]
    float* edge_out = (float*)d_out + (size_t)N * 16;  // [E,8]
    float* e_sum    = (float*)d_ws;                    // [N,8]

    hipMemsetAsync(e_sum, 0, (size_t)N * 8 * sizeof(float), stream);

    edge_kernel<<<NBLK, TB, 0, stream>>>(x, ei, attr, emb, w1, w2,
                                         edge_out, e_sum, E);

    node_kernel<<<(N + 255) / 256, 256, 0, stream>>>(x, e_sum, w_node, x_out, N);
}

// Round 9
// 197.955 us; speedup vs baseline: 2.3448x; 2.3448x over previous
//
#include <hip/hip_runtime.h>

// MGNConv fused-MFMA, round 9: TB=512 LDS-diet -> 2 blocks/CU with real slack.
//   edge_out[e,k] = sum_{c,ab} hs[e,c] * o[e,ab] * w2[c, ab*8+k]
//   hs = silu(emb@w1/4)/64  (folds both 1/8 path norms)
//   o[e,ab] = attr[e, ab>>4] * z[e, ab&15],  z = cat(x[vi], x[vj])
// Round-8 post-mortem: TB=1024 ALWAYS gets a 64-VGPR budget on this toolchain
// ((512,4), bare 1024, waves_per_eu, (1024,1) all spill). Only (512,2) is
// proven healthy (cap 128, no spill). Round-4 exact-fit 81920Bx2 didn't
// co-schedule -> need slack.
// Changes this round:
//  - back to TB=512, __launch_bounds__(512,2), NBLK=512
//  - zt stored as bf16 [16][32]/wave (8KB total), staged via cvt_pk + b16
//    writes, unpacked in epilogue by shl/and (the ushort4 halves need a
//    shift anyway)
//  - at (f32) + vj in wave-private LDS (round-5 pattern, round-4's
//    40-bpermute regression removed)
//  - LDS total 78848 B -> 2 blocks = 157696 <= 163840 with ~6KB slack

typedef __attribute__((ext_vector_type(8))) short short8;
typedef __attribute__((ext_vector_type(4))) float floatx4;

__device__ inline unsigned short f2bf(float f) {
    union { float f; unsigned u; } v; v.f = f;
    unsigned r = v.u + 0x7FFFu + ((v.u >> 16) & 1u);
    return (unsigned short)(r >> 16);
}
__device__ inline float bf2f(unsigned short u) {
    union { unsigned u; float f; } v; v.u = ((unsigned)u) << 16;
    return v.f;
}

__device__ inline unsigned cvt_pk_bf16(float lo, float hi) {
    unsigned r;
    asm("v_cvt_pk_bf16_f32 %0, %1, %2" : "=v"(r) : "v"(lo), "v"(hi));
    return r;
}

constexpr int TB    = 512;   // 8 waves
constexpr int NBLK  = 512;   // 2 blocks per CU (LDS = 78848 B)
constexpr int NWAVE = TB / 64;

constexpr int AT_LDF = 32;   // per wave [4][32] f32

__global__ __launch_bounds__(TB, 2)
void edge_kernel(
    const float* __restrict__ x,          // [N,8]
    const int*   __restrict__ ei,         // [2,E]
    const float* __restrict__ attr,       // [E,4]
    const float* __restrict__ emb,        // [E,16]
    const float* __restrict__ w1,         // [16,64]
    const float* __restrict__ w2,         // [64,512]
    float* __restrict__ edge_out,         // [E,8]
    float* __restrict__ e_sum,            // [N,8] pre-zeroed
    int E)
{
    // w2 transposed, bf16, XOR-swizzled: s_w2t[n*64 + (k ^ ((n&7)<<3))] = w2[k][n]
    __shared__ __align__(16) unsigned short s_w2t[512 * 64];           // 65536 B
    // z features bf16, per wave: [16 feat][32 edge]
    __shared__ __align__(16) unsigned short s_ztA[NWAVE * 16 * 32];    //  8192 B
    __shared__ __align__(16) float          s_atA[NWAVE * 4 * AT_LDF]; //  4096 B
    __shared__ int                          s_vjA[NWAVE * 32];         //  1024 B
    // total = 78848 B -> 2 blocks/CU (4 waves/SIMD)

    const int tid  = threadIdx.x;
    const int wave = tid >> 6;
    const int lane = tid & 63;
    const int m16  = lane & 15;
    const int quad = lane >> 4;
    const int par  = m16 >> 3;

    // ---- stage w2 transposed+swizzled to bf16 ----
    for (int idx = tid; idx < 512 * 64; idx += TB) {
        const int n = idx & 511, k = idx >> 9;
        s_w2t[n * 64 + (k ^ ((n & 7) << 3))] = f2bf(w2[k * 512 + n]);
    }
    __syncthreads();   // only barrier; steady loop is wave-private

    // ---- layer-1 w1 fragments (zero-padded K 16->32).
    // A-operand of the TRANSPOSED layer-1: A[m=chan mt*16+m16][k=quad*8+j] = w1[k][chan].
    short8 w1f[4];
    #pragma unroll
    for (int mt = 0; mt < 4; ++mt) {
        short8 f;
        if (quad < 2) {
            #pragma unroll
            for (int j = 0; j < 8; ++j)
                f[j] = (short)f2bf(w1[(quad * 8 + j) * 64 + mt * 16 + m16]);
        } else {
            #pragma unroll
            for (int j = 0; j < 8; ++j) f[j] = 0;
        }
        w1f[mt] = f;
    }

    unsigned short* ztw = s_ztA + wave * 16 * 32;
    float*          atw = s_atA + wave * 4 * AT_LDF;
    int*            vjw = s_vjA + wave * 32;

    const int  wid = blockIdx.x * NWAVE + wave;
    const int  nw  = NBLK * NWAVE;
    const int  ntiles = E >> 5;   // E divisible by 32 (800000)
    const bool stg = (quad < 2);
    const int  mst = quad * 16 + m16;   // == lane for stg lanes (0..31)

    // a2-gather shuffle source lanes
    const int srcA = m16 + 16 * ((2 * quad) & 3);
    const int srcB = m16 + 16 * ((2 * quad + 1) & 3);

    // swizzled b2 element offsets
    const int swz = (m16 & 7) << 3;
    const int o0  = (quad * 8) ^ swz;
    const int o1  = o0 ^ 32;

    // ---- pipeline registers (valid on stg lanes) ----
    float4 xi0, xi1, xj0, xj1, a4;
    float4 em0a, em0b, em1a, em1b;
    int viN = 0, vjN = 0, vjC = 0;

    // ---- prologue: tile wid data + ei for tile wid+nw ----
    if (wid < ntiles && stg) {
        const int e0 = (wid << 5) + mst;
        const int vi = ei[e0];
        vjC = ei[E + e0];
        xi0 = *(const float4*)(x + (size_t)vi * 8);
        xi1 = *(const float4*)(x + (size_t)vi * 8 + 4);
        xj0 = *(const float4*)(x + (size_t)vjC * 8);
        xj1 = *(const float4*)(x + (size_t)vjC * 8 + 4);
        a4  = *(const float4*)(attr + (size_t)e0 * 4);
        const float* ep0 = emb + (size_t)((wid << 5) + m16) * 16 + quad * 8;
        em0a = *(const float4*)ep0;
        em0b = *(const float4*)(ep0 + 4);
        const float* ep1 = emb + (size_t)((wid << 5) + 16 + m16) * 16 + quad * 8;
        em1a = *(const float4*)ep1;
        em1b = *(const float4*)(ep1 + 4);
        const int t1 = (wid + nw < ntiles) ? (wid + nw) : wid;
        const int e1 = (t1 << 5) + mst;
        viN = ei[e1];
        vjN = ei[E + e1];
    }

    for (int tile = wid; tile < ntiles; tile += nw) {
        const int base = tile << 5;

        // ---- A: stage z (bf16) / attr / vj to wave-private LDS ----
        if (stg) {
            unsigned w;
            w = cvt_pk_bf16(xi0.x, xi0.y);
            ztw[ 0*32+mst] = (unsigned short)w; ztw[ 1*32+mst] = (unsigned short)(w >> 16);
            w = cvt_pk_bf16(xi0.z, xi0.w);
            ztw[ 2*32+mst] = (unsigned short)w; ztw[ 3*32+mst] = (unsigned short)(w >> 16);
            w = cvt_pk_bf16(xi1.x, xi1.y);
            ztw[ 4*32+mst] = (unsigned short)w; ztw[ 5*32+mst] = (unsigned short)(w >> 16);
            w = cvt_pk_bf16(xi1.z, xi1.w);
            ztw[ 6*32+mst] = (unsigned short)w; ztw[ 7*32+mst] = (unsigned short)(w >> 16);
            w = cvt_pk_bf16(xj0.x, xj0.y);
            ztw[ 8*32+mst] = (unsigned short)w; ztw[ 9*32+mst] = (unsigned short)(w >> 16);
            w = cvt_pk_bf16(xj0.z, xj0.w);
            ztw[10*32+mst] = (unsigned short)w; ztw[11*32+mst] = (unsigned short)(w >> 16);
            w = cvt_pk_bf16(xj1.x, xj1.y);
            ztw[12*32+mst] = (unsigned short)w; ztw[13*32+mst] = (unsigned short)(w >> 16);
            w = cvt_pk_bf16(xj1.z, xj1.w);
            ztw[14*32+mst] = (unsigned short)w; ztw[15*32+mst] = (unsigned short)(w >> 16);
            atw[0*AT_LDF+mst]=a4.x;   atw[1*AT_LDF+mst]=a4.y;
            atw[2*AT_LDF+mst]=a4.z;   atw[3*AT_LDF+mst]=a4.w;
            vjw[mst] = vjC;
        }

        short8 a1[2];
        {
            union { short8 s8; unsigned u[4]; } uu;
            if (stg) {
                uu.u[0] = cvt_pk_bf16(em0a.x, em0a.y);
                uu.u[1] = cvt_pk_bf16(em0a.z, em0a.w);
                uu.u[2] = cvt_pk_bf16(em0b.x, em0b.y);
                uu.u[3] = cvt_pk_bf16(em0b.z, em0b.w);
            } else {
                uu.u[0]=0u; uu.u[1]=0u; uu.u[2]=0u; uu.u[3]=0u;
            }
            a1[0] = uu.s8;
            if (stg) {
                uu.u[0] = cvt_pk_bf16(em1a.x, em1a.y);
                uu.u[1] = cvt_pk_bf16(em1a.z, em1a.w);
                uu.u[2] = cvt_pk_bf16(em1b.x, em1b.y);
                uu.u[3] = cvt_pk_bf16(em1b.z, em1b.w);
            } else {
                uu.u[0]=0u; uu.u[1]=0u; uu.u[2]=0u; uu.u[3]=0u;
            }
            a1[1] = uu.s8;
        }

        // ---- B: issue next-tile loads into the just-consumed registers ----
        {
            const int tn     = tile + nw;
            const int tn_cl  = (tn  < ntiles) ? tn  : tile;
            const int tnn    = tn + nw;
            const int tnn_cl = (tnn < ntiles) ? tnn : tn_cl;
            if (stg) {
                const int en = (tn_cl << 5) + mst;
                vjC = vjN;   // vj of tile tn, staged at next A
                xi0 = *(const float4*)(x + (size_t)viN * 8);
                xi1 = *(const float4*)(x + (size_t)viN * 8 + 4);
                xj0 = *(const float4*)(x + (size_t)vjN * 8);
                xj1 = *(const float4*)(x + (size_t)vjN * 8 + 4);
                a4  = *(const float4*)(attr + (size_t)en * 4);
                const float* ep0 = emb + (size_t)((tn_cl << 5) + m16) * 16 + quad * 8;
                em0a = *(const float4*)ep0;
                em0b = *(const float4*)(ep0 + 4);
                const float* ep1 = emb + (size_t)((tn_cl << 5) + 16 + m16) * 16 + quad * 8;
                em1a = *(const float4*)ep1;
                em1b = *(const float4*)(ep1 + 4);
                const int enn = (tnn_cl << 5) + mst;
                viN = ei[enn];
                vjN = ei[E + enn];
            }
        }

        // ---- C: TRANSPOSED layer-1 MFMA -> silu -> a2 frags via shuffles.
        // C' = w1T @ embT: lane (m16,quad) holds edge s*16+m16,
        // chans {16mt + 4quad + r}. a2[s][qq] needs chans qq*32+quad*8+0..7
        // of the same edge. word w (chans c0=qq*32+quad*8+2w, c0+1) comes from
        // lane (m16, q'=(2quad+(w>>1))&3), reg p[mt'=2qq+(quad>>1)][w&1].
        short8 a2[2][2];
        #pragma unroll
        for (int s = 0; s < 2; ++s) {
            unsigned p[4][2];
            // pairs: keeps only 2 C-fragments (8 regs) live at a time
            #pragma unroll
            for (int half = 0; half < 2; ++half) {
                floatx4 c0, c1;
                {
                    floatx4 z4 = {0.f, 0.f, 0.f, 0.f};
                    c0 = __builtin_amdgcn_mfma_f32_16x16x32_bf16(w1f[2*half    ], a1[s], z4, 0, 0, 0);
                    c1 = __builtin_amdgcn_mfma_f32_16x16x32_bf16(w1f[2*half + 1], a1[s], z4, 0, 0, 0);
                }
                #pragma unroll
                for (int h = 0; h < 2; ++h) {
                    const floatx4& c = h ? c1 : c0;
                    float sv[4];
                    #pragma unroll
                    for (int r = 0; r < 4; ++r) {
                        const float u   = c[r] * 0.25f;               // /sqrt(16)
                        const float den = 1.f + __expf(-u);
                        sv[r] = u * __builtin_amdgcn_rcpf(den) * 0.015625f; // /64
                    }
                    p[2*half + h][0] = cvt_pk_bf16(sv[0], sv[1]);
                    p[2*half + h][1] = cvt_pk_bf16(sv[2], sv[3]);
                }
            }
            #pragma unroll
            for (int qq = 0; qq < 2; ++qq) {
                union { short8 s8; unsigned u[4]; } uu;
                #pragma unroll
                for (int w = 0; w < 4; ++w) {
                    const int srcLane = (w < 2) ? srcA : srcB;
                    const unsigned vA = (unsigned)__shfl((int)p[2*qq    ][w & 1], srcLane, 64);
                    const unsigned vB = (unsigned)__shfl((int)p[2*qq + 1][w & 1], srcLane, 64);
                    uu.u[w] = (quad & 2) ? vB : vA;
                }
                a2[s][qq] = uu.s8;
            }
        }

        float eacc[2][4];
        #pragma unroll
        for (int s = 0; s < 2; ++s)
            #pragma unroll
            for (int r = 0; r < 4; ++r) eacc[s][r] = 0.f;

        // ---- D: N loop, defer-attr epilogue; attr from wave-private LDS.
        // b_idx = (2t+par)&15 == (2tt+par)&15 (g-independent)
        __builtin_amdgcn_s_setprio(1);
        #pragma unroll 1
        for (int g = 0; g < 4; ++g) {
            float av[2][4];
            #pragma unroll
            for (int s = 0; s < 2; ++s) {
                const float4 a4v = *(const float4*)(atw + g * AT_LDF + s * 16 + quad * 4);
                av[s][0] = a4v.x; av[s][1] = a4v.y;
                av[s][2] = a4v.z; av[s][3] = a4v.w;
            }

            float tacc[2][4];
            #pragma unroll
            for (int s = 0; s < 2; ++s)
                #pragma unroll
                for (int r = 0; r < 4; ++r) tacc[s][r] = 0.f;

            #pragma unroll
            for (int tt = 0; tt < 8; ++tt) {
                const int t = g * 8 + tt;
                const unsigned short* wrow = s_w2t + (16 * t + m16) * 64;
                short8 b2[2];
                b2[0] = *(const short8*)(wrow + o0);
                b2[1] = *(const short8*)(wrow + o1);
                const int b_idx = (2 * tt + par) & 15;
                #pragma unroll
                for (int s = 0; s < 2; ++s) {
                    floatx4 c = {0.f, 0.f, 0.f, 0.f};
                    c = __builtin_amdgcn_mfma_f32_16x16x32_bf16(a2[s][0], b2[0], c, 0, 0, 0);
                    c = __builtin_amdgcn_mfma_f32_16x16x32_bf16(a2[s][1], b2[1], c, 0, 0, 0);
                    const ushort4 zu = *(const ushort4*)(ztw + b_idx * 32 + s * 16 + quad * 4);
                    tacc[s][0] = fmaf(c[0], bf2f(zu.x), tacc[s][0]);
                    tacc[s][1] = fmaf(c[1], bf2f(zu.y), tacc[s][1]);
                    tacc[s][2] = fmaf(c[2], bf2f(zu.z), tacc[s][2]);
                    tacc[s][3] = fmaf(c[3], bf2f(zu.w), tacc[s][3]);
                }
            }
            #pragma unroll
            for (int s = 0; s < 2; ++s)
                #pragma unroll
                for (int r = 0; r < 4; ++r)
                    eacc[s][r] = fmaf(av[s][r], tacc[s][r], eacc[s][r]);
        }
        __builtin_amdgcn_s_setprio(0);

        // ---- E: reduce ab-parity (lanes col and col^8), then write ----
        #pragma unroll
        for (int s = 0; s < 2; ++s)
            #pragma unroll
            for (int r = 0; r < 4; ++r)
                eacc[s][r] += __shfl_xor(eacc[s][r], 8, 64);

        if (m16 < 8) {
            #pragma unroll
            for (int s = 0; s < 2; ++s) {
                const int4 vjq = *(const int4*)(vjw + s * 16 + quad * 4);
                const int vjr[4] = {vjq.x, vjq.y, vjq.z, vjq.w};
                #pragma unroll
                for (int r = 0; r < 4; ++r) {
                    const int e = base + s * 16 + quad * 4 + r;
                    edge_out[(size_t)e * 8 + m16] = eacc[s][r];
                    atomicAdd(e_sum + (size_t)vjr[r] * 8 + m16, eacc[s][r]);
                }
            }
        }
    }
}

__global__ __launch_bounds__(256) void node_kernel(
    const float* __restrict__ x,       // [N,8]
    const float* __restrict__ e_sum,   // [N,8]
    const float* __restrict__ w_node,  // [8,8,16]
    float* __restrict__ x_out,         // [N,16]
    int N)
{
    __shared__ float s_w[8 * 8 * 16];
    for (int idx = threadIdx.x; idx < 1024; idx += 256) s_w[idx] = w_node[idx];
    __syncthreads();

    const int n = blockIdx.x * 256 + threadIdx.x;
    if (n >= N) return;

    float xa[8], eb[8];
    #pragma unroll
    for (int a = 0; a < 8; ++a) xa[a] = x[(size_t)n * 8 + a];
    #pragma unroll
    for (int b = 0; b < 8; ++b) eb[b] = e_sum[(size_t)n * 8 + b];

    float out[16];
    #pragma unroll
    for (int k = 0; k < 16; ++k) out[k] = 0.f;

    const float4* wv = (const float4*)s_w;
    #pragma unroll
    for (int a = 0; a < 8; ++a) {
        #pragma unroll
        for (int b = 0; b < 8; ++b) {
            const float t = xa[a] * eb[b] * 0.125f;
            #pragma unroll
            for (int k4 = 0; k4 < 4; ++k4) {
                const float4 w = wv[(a * 8 + b) * 4 + k4];
                out[k4 * 4 + 0] = fmaf(t, w.x, out[k4 * 4 + 0]);
                out[k4 * 4 + 1] = fmaf(t, w.y, out[k4 * 4 + 1]);
                out[k4 * 4 + 2] = fmaf(t, w.z, out[k4 * 4 + 2]);
                out[k4 * 4 + 3] = fmaf(t, w.w, out[k4 * 4 + 3]);
            }
        }
    }

    float4* xo = (float4*)(x_out + (size_t)n * 16);
    #pragma unroll
    for (int k4 = 0; k4 < 4; ++k4)
        xo[k4] = make_float4(out[k4 * 4 + 0], out[k4 * 4 + 1],
                             out[k4 * 4 + 2], out[k4 * 4 + 3]);
}

extern "C" void kernel_launch(void* const* d_in, const int* in_sizes, int n_in,
                              void* d_out, int out_size, void* d_ws, size_t ws_size,
                              hipStream_t stream) {
    const float* x      = (const float*)d_in[0];
    const int*   ei     = (const int*)d_in[1];
    const float* attr   = (const float*)d_in[2];
    const float* emb    = (const float*)d_in[3];
    const float* w1     = (const float*)d_in[4];
    const float* w2     = (const float*)d_in[5];
    const float* w_node = (const float*)d_in[6];

    const int N = in_sizes[0] / 8;   // 50000
    const int E = in_sizes[2] / 4;   // 800000

    float* x_out    = (float*)d_out;                   // [N,16]
    float* edge_out = (float*)d_out + (size_t)N * 16;  // [E,8]
    float* e_sum    = (float*)d_ws;                    // [N,8]

    hipMemsetAsync(e_sum, 0, (size_t)N * 8 * sizeof(float), stream);

    edge_kernel<<<NBLK, TB, 0, stream>>>(x, ei, attr, emb, w1, w2,
                                         edge_out, e_sum, E);

    node_kernel<<<(N + 255) / 256, 256, 0, stream>>>(x, e_sum, w_node, x_out, N);
}